// Round 13
// baseline (469.014 us; speedup 1.0000x reference)
//
#include <hip/hip_runtime.h>
#include <hip/hip_bf16.h>

#define N_NODES 50000
#define E_EDGES 800000
#define ET (E_EDGES + N_NODES)
#define G_GRAPHS 64
#define IN_F 128
#define HID 64
#define HEADS 4
#define HC (HID * HEADS)
#define NC 2
#define SLOPE 0.2f
#define L2E 1.4426950408889634f

typedef float f32x4 __attribute__((ext_vector_type(4)));
typedef __bf16 bf16x8 __attribute__((ext_vector_type(8)));
typedef unsigned short us8 __attribute__((ext_vector_type(8)));
typedef unsigned short us4 __attribute__((ext_vector_type(4)));
typedef _Float16 h16x4 __attribute__((ext_vector_type(4)));

#define MFMA16(a, b, c) \
  __builtin_amdgcn_mfma_f32_16x16x32_bf16(__builtin_bit_cast(bf16x8, (a)), \
                                          __builtin_bit_cast(bf16x8, (b)), (c), 0, 0, 0)

__device__ inline unsigned short f2bf_rne(float f) {
  unsigned u = __builtin_bit_cast(unsigned, f);
  u += 0x7fffu + ((u >> 16) & 1u);
  return (unsigned short)(u >> 16);
}
__device__ inline float bf2f(unsigned short h) {
  unsigned u = ((unsigned)h) << 16;
  return __builtin_bit_cast(float, u);
}

// ---------------- fused split/cast kernel ----------------

__device__ inline void split4(const float* __restrict__ in, unsigned short* __restrict__ hi,
                              unsigned short* __restrict__ lo, int i) {
  float4 v = *(const float4*)&in[i];
  float f[4] = {v.x, v.y, v.z, v.w};
  us4 h, l;
#pragma unroll
  for (int j = 0; j < 4; j++) {
    unsigned short hb = f2bf_rne(f[j]);
    h[j] = hb;
    l[j] = f2bf_rne(f[j] - bf2f(hb));
  }
  *(us4*)&hi[i] = h;
  *(us4*)&lo[i] = l;
}

#define QX (N_NODES * IN_F / 4)
#define QW1 (HC * IN_F / 4)
#define QW2 (HC * HC / 4)
#define QTOT (QX + QW1 + 2 * QW2)

__global__ __launch_bounds__(256) void split_all_kernel(
    const float* __restrict__ x, const float* __restrict__ W1,
    const float* __restrict__ W2, const float* __restrict__ W3,
    unsigned short* __restrict__ xhi,
    unsigned short* __restrict__ w1h, unsigned short* __restrict__ w1l,
    unsigned short* __restrict__ w2h, unsigned short* __restrict__ w2l,
    unsigned short* __restrict__ w3h, unsigned short* __restrict__ w3l) {
  int q = blockIdx.x * 256 + threadIdx.x;
  if (q < QX) {
    int i = q * 4;
    float4 v = *(const float4*)&x[i];
    float f[4] = {v.x, v.y, v.z, v.w};
    us4 h;
#pragma unroll
    for (int j = 0; j < 4; j++) h[j] = f2bf_rne(f[j]);
    *(us4*)&xhi[i] = h;
  } else if (q < QX + QW1) {
    split4(W1, w1h, w1l, (q - QX) * 4);
  } else if (q < QX + QW1 + QW2) {
    split4(W2, w2h, w2l, (q - QX - QW1) * 4);
  } else {
    split4(W3, w3h, w3l, (q - QX - QW1 - QW2) * 4);
  }
}

// ---------------- CSR build ----------------

__global__ void count_kernel(const int* __restrict__ ei, int* __restrict__ cnt) {
  int e = blockIdx.x * blockDim.x + threadIdx.x;
  if (e >= ET) return;
  int dst = (e < E_EDGES) ? ei[E_EDGES + e] : (e - E_EDGES);
  atomicAdd(&cnt[dst], 1);
}

#define SCAN_BLOCKS ((N_NODES + 255) / 256)

__global__ __launch_bounds__(256) void scan1_kernel(const int* __restrict__ cnt,
                                                    int* __restrict__ incl_buf,
                                                    int* __restrict__ partial) {
  __shared__ int ws[4];
  int tid = threadIdx.x, b = blockIdx.x;
  int wave = tid >> 6, lane = tid & 63;
  int i = b * 256 + tid;
  int v = (i < N_NODES) ? cnt[i] : 0;
  int x = v;
#pragma unroll
  for (int off = 1; off < 64; off <<= 1) {
    int t = __shfl_up(x, off, 64);
    if (lane >= off) x += t;
  }
  if (lane == 63) ws[wave] = x;
  __syncthreads();
  if (tid == 0) {
    int s = 0;
#pragma unroll
    for (int w = 0; w < 4; w++) { int t = ws[w]; ws[w] = s; s += t; }
    partial[b] = s;
  }
  __syncthreads();
  if (i < N_NODES) incl_buf[i] = x + ws[wave];
}

__global__ __launch_bounds__(256) void scan2_kernel(int* __restrict__ partial) {
  __shared__ int ws[4];
  int tid = threadIdx.x;
  int wave = tid >> 6, lane = tid & 63;
  int v = (tid < SCAN_BLOCKS) ? partial[tid] : 0;
  int x = v;
#pragma unroll
  for (int off = 1; off < 64; off <<= 1) {
    int t = __shfl_up(x, off, 64);
    if (lane >= off) x += t;
  }
  if (lane == 63) ws[wave] = x;
  __syncthreads();
  if (tid == 0) {
    int s = 0;
#pragma unroll
    for (int w = 0; w < 4; w++) { int t = ws[w]; ws[w] = s; s += t; }
  }
  __syncthreads();
  partial[tid] = x + ws[wave] - v;
}

__global__ __launch_bounds__(256) void scan3_kernel(const int* __restrict__ cnt,
                                                    int* __restrict__ incl_buf,
                                                    const int* __restrict__ partial,
                                                    int* __restrict__ rowptr,
                                                    int* __restrict__ cursor) {
  int tid = threadIdx.x, b = blockIdx.x;
  int i = b * 256 + tid;
  if (i >= N_NODES) return;
  int incl = incl_buf[i] + partial[b];
  rowptr[i + 1] = incl;
  cursor[i] = incl - cnt[i];
  if (i == 0) rowptr[0] = 0;
}

__global__ void scatter_kernel(const int* __restrict__ ei, int* __restrict__ cursor,
                               int* __restrict__ csr_src) {
  int e = blockIdx.x * blockDim.x + threadIdx.x;
  if (e >= ET) return;
  int src, dst;
  if (e < E_EDGES) { src = ei[e]; dst = ei[E_EDGES + e]; }
  else { src = e - E_EDGES; dst = src; }
  int pos = atomicAdd(&cursor[dst], 1);
  csr_src[pos] = src;
}

// ---------------- 2-term split-bf16 MFMA GEMM, LDS-FREE ----------------
// BM=64 (782 blocks), BN=256, BK=32. 4 waves; wave w = head w, 64x64 sub-tile.
// N=256 is tiny: LDS staging was pure overhead (R12 diagnosis: ~170 LDS ops +
// 2 barriers per wave per K-iter to stage a B-tile identical across all blocks).
// Every MFMA fragment is 16B contiguous in global memory -> load DIRECTLY
// global->VGPR. A coalesces 64B/row-quad; W (<=128KB) is L2-resident.
// Register double-buffer across K-iters; zero barriers, pure dataflow.
// Tail rows clamp to N-1 (their outputs are never stored/read).

template <int K>
__global__ __launch_bounds__(256) void mfma_gemm_kernel(
    const unsigned short* __restrict__ A,
    const unsigned short* __restrict__ Whi, const unsigned short* __restrict__ Wlo,
    const float* __restrict__ a_s, const float* __restrict__ a_d,
    _Float16* __restrict__ hbuf16, float* __restrict__ als, float* __restrict__ ald) {
  int t = threadIdx.x;
  int mt = blockIdx.x;
  int w = t >> 6, lane = t & 63, lr = lane & 15, kg = lane >> 4;

  f32x4 acc[4][4];
#pragma unroll
  for (int m = 0; m < 4; m++)
#pragma unroll
    for (int nf = 0; nf < 4; nf++) {
      f32x4 z = {0.f, 0.f, 0.f, 0.f};
      acc[m][nf] = z;
    }

  // per-lane fragment base pointers
  const unsigned short* ap[4];
#pragma unroll
  for (int m = 0; m < 4; m++) {
    int row = min(mt * 64 + m * 16 + lr, N_NODES - 1);
    ap[m] = A + (size_t)row * K + kg * 8;
  }
  const unsigned short *bph[4], *bpl[4];
#pragma unroll
  for (int nf = 0; nf < 4; nf++) {
    int n = w * 64 + nf * 16 + lr;
    bph[nf] = Whi + (size_t)n * K + kg * 8;
    bpl[nf] = Wlo + (size_t)n * K + kg * 8;
  }

  us8 af[2][4], bh[2][4], bl[2][4];
  // prefetch k-tile 0
#pragma unroll
  for (int m = 0; m < 4; m++) af[0][m] = *(const us8*)ap[m];
#pragma unroll
  for (int nf = 0; nf < 4; nf++) {
    bh[0][nf] = *(const us8*)bph[nf];
    bl[0][nf] = *(const us8*)bpl[nf];
  }

#pragma unroll
  for (int k0 = 0; k0 < K; k0 += 32) {
    const int buf = (k0 >> 5) & 1;
    const int nbuf = buf ^ 1;
    if (k0 + 32 < K) {
      int k1 = k0 + 32;
#pragma unroll
      for (int m = 0; m < 4; m++) af[nbuf][m] = *(const us8*)(ap[m] + k1);
#pragma unroll
      for (int nf = 0; nf < 4; nf++) {
        bh[nbuf][nf] = *(const us8*)(bph[nf] + k1);
        bl[nbuf][nf] = *(const us8*)(bpl[nf] + k1);
      }
    }
#pragma unroll
    for (int m = 0; m < 4; m++) {
#pragma unroll
      for (int nf = 0; nf < 4; nf++) {
        acc[m][nf] = MFMA16(af[buf][m], bh[buf][nf], acc[m][nf]);
        acc[m][nf] = MFMA16(af[buf][m], bl[buf][nf], acc[m][nf]);
      }
    }
  }

  // epilogue: store h (fp16) + reduce als/ald (scaled by log2e) for head w.
  // C layout: col = nf*16 + lr, row = m*16 + kg*4 + r
  int head = w;
  float asv[4], adv[4];
#pragma unroll
  for (int nf = 0; nf < 4; nf++) {
    asv[nf] = a_s[head * HID + nf * 16 + lr];
    adv[nf] = a_d[head * HID + nf * 16 + lr];
  }
#pragma unroll
  for (int m = 0; m < 4; m++) {
#pragma unroll
    for (int r = 0; r < 4; r++) {
      int grow = mt * 64 + m * 16 + kg * 4 + r;
      float ps = 0.f, pd = 0.f;
#pragma unroll
      for (int nf = 0; nf < 4; nf++) {
        float v = acc[m][nf][r];
        ps += v * asv[nf];
        pd += v * adv[nf];
        if (grow < N_NODES)
          hbuf16[(size_t)grow * HC + head * 64 + nf * 16 + lr] = (_Float16)v;
      }
#pragma unroll
      for (int msk = 1; msk < 16; msk <<= 1) {
        ps += __shfl_xor(ps, msk, 64);
        pd += __shfl_xor(pd, msk, 64);
      }
      if (lr == 0 && grow < N_NODES) {
        als[grow * HEADS + head] = ps * L2E;
        ald[grow * HEADS + head] = pd * L2E;
      }
    }
  }
}

// ---------------- dual-stream per-destination softmax + aggregate (R7 keeper) ----------------

template <int MODE>
__global__ __launch_bounds__(256) void agg_kernel(
    const _Float16* __restrict__ hbuf16, const float* __restrict__ alsE,
    const float* __restrict__ aldE, const int* __restrict__ rowptr,
    const int* __restrict__ csr_src, const float* __restrict__ bias,
    unsigned short* __restrict__ ohi, float* __restrict__ pooled,
    const int* __restrict__ batch) {
  int wave = threadIdx.x >> 6;
  int lane = threadIdx.x & 63;
  int v0 = blockIdx.x * 8 + wave * 2;
  int v1 = v0 + 1;
  int head = lane >> 4;
  float ald0 = aldE[(unsigned)v0 * HEADS + head];
  float ald1 = aldE[(unsigned)v1 * HEADS + head];
  int beg0 = rowptr[v0], n0 = rowptr[v0 + 1] - beg0;
  int beg1 = rowptr[v1], n1 = rowptr[v1 + 1] - beg1;
  int n = max(n0, n1);

  float den0 = 0.f, den1 = 0.f;
  f32x4 acc0 = {0.f, 0.f, 0.f, 0.f};
  f32x4 acc1 = {0.f, 0.f, 0.f, 0.f};
  const _Float16* hp = hbuf16 + (lane << 2);
#pragma unroll 2
  for (int i = 0; i < n; i++) {
    int s0 = csr_src[beg0 + min(i, n0 - 1)];
    int s1 = csr_src[beg1 + min(i, n1 - 1)];
    float a0 = alsE[(unsigned)s0 * HEADS + head] + ald0;
    float a1 = alsE[(unsigned)s1 * HEADS + head] + ald1;
    a0 = fmaxf(a0, SLOPE * a0);
    a1 = fmaxf(a1, SLOPE * a1);
    float ex0 = (i < n0) ? __builtin_amdgcn_exp2f(a0) : 0.f;
    float ex1 = (i < n1) ? __builtin_amdgcn_exp2f(a1) : 0.f;
    h16x4 h0 = *(const h16x4*)(hp + ((unsigned)s0 << 8));
    h16x4 h1 = *(const h16x4*)(hp + ((unsigned)s1 << 8));
    den0 += ex0; den1 += ex1;
    acc0[0] += (float)h0[0] * ex0; acc0[1] += (float)h0[1] * ex0;
    acc0[2] += (float)h0[2] * ex0; acc0[3] += (float)h0[3] * ex0;
    acc1[0] += (float)h1[0] * ex1; acc1[1] += (float)h1[1] * ex1;
    acc1[2] += (float)h1[2] * ex1; acc1[3] += (float)h1[3] * ex1;
  }
  float inv0 = 1.0f / (den0 + 1e-16f);
  float inv1 = 1.0f / (den1 + 1e-16f);
  float4 bv = *(const float4*)&bias[lane * 4];
  float o0[4], o1[4];
  o0[0] = acc0[0] * inv0 + bv.x; o0[1] = acc0[1] * inv0 + bv.y;
  o0[2] = acc0[2] * inv0 + bv.z; o0[3] = acc0[3] * inv0 + bv.w;
  o1[0] = acc1[0] * inv1 + bv.x; o1[1] = acc1[1] * inv1 + bv.y;
  o1[2] = acc1[2] * inv1 + bv.z; o1[3] = acc1[3] * inv1 + bv.w;

  if (MODE == 0) {
    us4 h0, h1;
#pragma unroll
    for (int j = 0; j < 4; j++) {
      h0[j] = f2bf_rne(fmaxf(o0[j], 0.f));
      h1[j] = f2bf_rne(fmaxf(o1[j], 0.f));
    }
    *(us4*)&ohi[(size_t)v0 * HC + lane * 4] = h0;
    *(us4*)&ohi[(size_t)v1 * HC + lane * 4] = h1;
  } else {
    __shared__ float pacc[8][HC];
    __shared__ int pg[8];
    f32x4 ov0 = {o0[0], o0[1], o0[2], o0[3]};
    f32x4 ov1 = {o1[0], o1[1], o1[2], o1[3]};
    *(f32x4*)&pacc[wave * 2][lane * 4] = ov0;
    *(f32x4*)&pacc[wave * 2 + 1][lane * 4] = ov1;
    if (lane == 0) {
      pg[wave * 2] = batch[v0];
      pg[wave * 2 + 1] = batch[v1];
    }
    __syncthreads();
    int c = threadIdx.x;
    float s = pacc[0][c];
    int gcur = pg[0];
#pragma unroll
    for (int wv = 1; wv < 8; wv++) {
      if (pg[wv] != gcur) {
        atomicAdd(&pooled[gcur * HC + c], s);
        s = 0.f;
        gcur = pg[wv];
      }
      s += pacc[wv][c];
    }
    atomicAdd(&pooled[gcur * HC + c], s);
  }
}

// ---------------- MLP head (fused mean-divide) ----------------

__global__ __launch_bounds__(64) void mlp_kernel(const float* __restrict__ pooled_sum,
                                                 const int* __restrict__ batch,
                                                 const float* __restrict__ w1,
                                                 const float* __restrict__ b1,
                                                 const float* __restrict__ w2,
                                                 const float* __restrict__ b2,
                                                 float* __restrict__ out) {
  int g = blockIdx.x;
  int j = threadIdx.x;
  int lo = 0, hi = N_NODES;
  while (lo < hi) { int mid = (lo + hi) >> 1; if (batch[mid] < g) lo = mid + 1; else hi = mid; }
  int start = lo;
  hi = N_NODES;
  while (lo < hi) { int mid = (lo + hi) >> 1; if (batch[mid] < g + 1) lo = mid + 1; else hi = mid; }
  float invc = 1.0f / fmaxf((float)(lo - start), 1.0f);
  __shared__ float z[HID];
  float acc = 0.f;
  for (int k = 0; k < HC; k++) acc += pooled_sum[g * HC + k] * w1[j * HC + k];
  z[j] = fmaxf(acc * invc + b1[j], 0.f);
  __syncthreads();
  if (j < NC) {
    float o = b2[j];
    for (int k = 0; k < HID; k++) o += z[k] * w2[j * HID + k];
    out[g * NC + j] = o;
  }
}

// ---------------- launch ----------------

extern "C" void kernel_launch(void* const* d_in, const int* in_sizes, int n_in,
                              void* d_out, int out_size, void* d_ws, size_t ws_size,
                              hipStream_t stream) {
  const float* x    = (const float*)d_in[0];
  const int*   ei   = (const int*)d_in[1];
  const int*   batch= (const int*)d_in[2];
  const float* W1   = (const float*)d_in[3];
  const float* as1  = (const float*)d_in[4];
  const float* ad1  = (const float*)d_in[5];
  const float* b1   = (const float*)d_in[6];
  const float* W2   = (const float*)d_in[7];
  const float* as2  = (const float*)d_in[8];
  const float* ad2  = (const float*)d_in[9];
  const float* b2   = (const float*)d_in[10];
  const float* W3   = (const float*)d_in[11];
  const float* as3  = (const float*)d_in[12];
  const float* ad3  = (const float*)d_in[13];
  const float* b3   = (const float*)d_in[14];
  const float* fc1w = (const float*)d_in[15];
  const float* fc1b = (const float*)d_in[16];
  const float* fc2w = (const float*)d_in[17];
  const float* fc2b = (const float*)d_in[18];
  float* out = (float*)d_out;

  char* ws = (char*)d_ws;
  size_t off = 0;
  _Float16* hbuf16 = (_Float16*)(ws + off); off += (size_t)N_NODES * HC * 2;
  unsigned short* ahi = (unsigned short*)(ws + off); off += (size_t)N_NODES * HC * 2;
  unsigned short* xhi = (unsigned short*)(ws + off); off += (size_t)N_NODES * IN_F * 2;
  unsigned short* w1h = (unsigned short*)(ws + off); off += (size_t)HC * IN_F * 2;
  unsigned short* w1l = (unsigned short*)(ws + off); off += (size_t)HC * IN_F * 2;
  unsigned short* w2h = (unsigned short*)(ws + off); off += (size_t)HC * HC * 2;
  unsigned short* w2l = (unsigned short*)(ws + off); off += (size_t)HC * HC * 2;
  unsigned short* w3h = (unsigned short*)(ws + off); off += (size_t)HC * HC * 2;
  unsigned short* w3l = (unsigned short*)(ws + off); off += (size_t)HC * HC * 2;
  float* als    = (float*)(ws + off); off += (size_t)N_NODES * HEADS * 4;
  float* ald    = (float*)(ws + off); off += (size_t)N_NODES * HEADS * 4;
  float* pooled = (float*)(ws + off); off += (size_t)G_GRAPHS * HC * 4;
  int*   cnt    = (int*)(ws + off);   off += (size_t)N_NODES * 4;
  int*   cursor = (int*)(ws + off);   off += (size_t)N_NODES * 4;
  int*   csrsrc = (int*)(ws + off);   off += (size_t)ET * 4;
  int*   rowptr = (int*)(ws + off);   off += (size_t)(N_NODES + 1) * 4;
  int*   partial= (int*)(ws + off);   off += 256 * 4;

  // --- fused splits (independent of CSR) ---
  split_all_kernel<<<(QTOT + 255) / 256, 256, 0, stream>>>(
      x, W1, W2, W3, xhi, w1h, w1l, w2h, w2l, w3h, w3l);

  // --- CSR build ---
  hipMemsetAsync(cnt, 0, (size_t)N_NODES * 4, stream);
  hipMemsetAsync(pooled, 0, (size_t)G_GRAPHS * HC * 4, stream);
  count_kernel<<<(ET + 255) / 256, 256, 0, stream>>>(ei, cnt);
  scan1_kernel<<<SCAN_BLOCKS, 256, 0, stream>>>(cnt, cursor, partial);
  scan2_kernel<<<1, 256, 0, stream>>>(partial);
  scan3_kernel<<<SCAN_BLOCKS, 256, 0, stream>>>(cnt, cursor, partial, rowptr, cursor);
  scatter_kernel<<<(ET + 255) / 256, 256, 0, stream>>>(ei, cursor, csrsrc);

  dim3 gemm_grid((N_NODES + 63) / 64);
  int agg_grid = N_NODES / 8;  // exact: 50000 % 8 == 0

  // --- layer 1 ---
  mfma_gemm_kernel<IN_F><<<gemm_grid, 256, 0, stream>>>(xhi, w1h, w1l, as1, ad1, hbuf16, als, ald);
  agg_kernel<0><<<agg_grid, 256, 0, stream>>>(hbuf16, als, ald, rowptr, csrsrc, b1, ahi, nullptr, nullptr);
  // --- layer 2 ---
  mfma_gemm_kernel<HC><<<gemm_grid, 256, 0, stream>>>(ahi, w2h, w2l, as2, ad2, hbuf16, als, ald);
  agg_kernel<0><<<agg_grid, 256, 0, stream>>>(hbuf16, als, ald, rowptr, csrsrc, b2, ahi, nullptr, nullptr);
  // --- layer 3 (fused mean-pool accumulate) ---
  mfma_gemm_kernel<HC><<<gemm_grid, 256, 0, stream>>>(ahi, w3h, w3l, as3, ad3, hbuf16, als, ald);
  agg_kernel<1><<<agg_grid, 256, 0, stream>>>(hbuf16, als, ald, rowptr, csrsrc, b3, nullptr, pooled, batch);

  // --- MLP (with fused mean divide) ---
  mlp_kernel<<<G_GRAPHS, 64, 0, stream>>>(pooled, batch, fc1w, fc1b, fc2w, fc2b, out);
}

// Round 14
// 446.694 us; speedup vs baseline: 1.0500x; 1.0500x over previous
//
#include <hip/hip_runtime.h>
#include <hip/hip_bf16.h>

#define N_NODES 50000
#define NPAD (N_NODES + 64)
#define E_EDGES 800000
#define ET (E_EDGES + N_NODES)
#define G_GRAPHS 64
#define IN_F 128
#define HID 64
#define HEADS 4
#define HC (HID * HEADS)
#define NC 2
#define SLOPE 0.2f
#define L2E 1.4426950408889634f

typedef float f32x4 __attribute__((ext_vector_type(4)));
typedef __bf16 bf16x8 __attribute__((ext_vector_type(8)));
typedef unsigned short us8 __attribute__((ext_vector_type(8)));
typedef unsigned short us4 __attribute__((ext_vector_type(4)));
typedef _Float16 h16x4 __attribute__((ext_vector_type(4)));

#define MFMA16(a, b, c) \
  __builtin_amdgcn_mfma_f32_16x16x32_bf16(__builtin_bit_cast(bf16x8, (a)), \
                                          __builtin_bit_cast(bf16x8, (b)), (c), 0, 0, 0)

__device__ inline unsigned short f2bf_rne(float f) {
  unsigned u = __builtin_bit_cast(unsigned, f);
  u += 0x7fffu + ((u >> 16) & 1u);
  return (unsigned short)(u >> 16);
}
__device__ inline float bf2f(unsigned short h) {
  unsigned u = ((unsigned)h) << 16;
  return __builtin_bit_cast(float, u);
}

// ---------------- fused split/cast + wals precompute kernel ----------------
// wals[j][k] = L2E * sum_c a_j[c] * W[(j&3)*64+c][k]   (j<4: a_src, j>=4: a_dst)
// -> als/ald become extra MFMA columns in the GEMM (kills the shuffle epilogue).

__device__ inline void split4(const float* __restrict__ in, unsigned short* __restrict__ hi,
                              unsigned short* __restrict__ lo, int i) {
  float4 v = *(const float4*)&in[i];
  float f[4] = {v.x, v.y, v.z, v.w};
  us4 h, l;
#pragma unroll
  for (int j = 0; j < 4; j++) {
    unsigned short hb = f2bf_rne(f[j]);
    h[j] = hb;
    l[j] = f2bf_rne(f[j] - bf2f(hb));
  }
  *(us4*)&hi[i] = h;
  *(us4*)&lo[i] = l;
}

#define QX (N_NODES * IN_F / 4)
#define QW1 (HC * IN_F / 4)
#define QW2 (HC * HC / 4)
#define QTOT (QX + QW1 + 2 * QW2)
#define QWALS (8 * IN_F + 8 * HC + 8 * HC)
#define QALL (QTOT + QWALS)

__global__ __launch_bounds__(256) void split_all_kernel(
    const float* __restrict__ x, const float* __restrict__ W1,
    const float* __restrict__ W2, const float* __restrict__ W3,
    const float* __restrict__ as1, const float* __restrict__ ad1,
    const float* __restrict__ as2, const float* __restrict__ ad2,
    const float* __restrict__ as3, const float* __restrict__ ad3,
    unsigned short* __restrict__ xhi,
    unsigned short* __restrict__ w1h, unsigned short* __restrict__ w1l,
    unsigned short* __restrict__ w2h, unsigned short* __restrict__ w2l,
    unsigned short* __restrict__ w3h, unsigned short* __restrict__ w3l,
    unsigned short* __restrict__ wa1h, unsigned short* __restrict__ wa1l,
    unsigned short* __restrict__ wa2h, unsigned short* __restrict__ wa2l,
    unsigned short* __restrict__ wa3h, unsigned short* __restrict__ wa3l) {
  int q = blockIdx.x * 256 + threadIdx.x;
  if (q < QX) {
    int i = q * 4;
    float4 v = *(const float4*)&x[i];
    float f[4] = {v.x, v.y, v.z, v.w};
    us4 h;
#pragma unroll
    for (int j = 0; j < 4; j++) h[j] = f2bf_rne(f[j]);
    *(us4*)&xhi[i] = h;
  } else if (q < QX + QW1) {
    split4(W1, w1h, w1l, (q - QX) * 4);
  } else if (q < QX + QW1 + QW2) {
    split4(W2, w2h, w2l, (q - QX - QW1) * 4);
  } else if (q < QTOT) {
    split4(W3, w3h, w3l, (q - QX - QW1 - QW2) * 4);
  } else if (q < QALL) {
    int q2 = q - QTOT;
    const float *W, *av;
    unsigned short *wh, *wl;
    int j, k, K;
    if (q2 < 8 * IN_F) {
      j = q2 >> 7; k = q2 & (IN_F - 1); K = IN_F;
      W = W1; av = (j < 4) ? as1 : ad1; wh = wa1h; wl = wa1l;
    } else if (q2 < 8 * IN_F + 8 * HC) {
      int r = q2 - 8 * IN_F;
      j = r >> 8; k = r & (HC - 1); K = HC;
      W = W2; av = (j < 4) ? as2 : ad2; wh = wa2h; wl = wa2l;
    } else {
      int r = q2 - 8 * IN_F - 8 * HC;
      j = r >> 8; k = r & (HC - 1); K = HC;
      W = W3; av = (j < 4) ? as3 : ad3; wh = wa3h; wl = wa3l;
    }
    int head = j & 3;
    float s = 0.f;
    for (int c = 0; c < HID; c++)
      s += av[head * HID + c] * W[(size_t)(head * HID + c) * K + k];
    s *= L2E;
    unsigned short hb = f2bf_rne(s);
    wh[j * K + k] = hb;
    wl[j * K + k] = f2bf_rne(s - bf2f(hb));
  }
}

// ---------------- CSR build ----------------

__global__ void count_kernel(const int* __restrict__ ei, int* __restrict__ cnt) {
  int e = blockIdx.x * blockDim.x + threadIdx.x;
  if (e >= ET) return;
  int dst = (e < E_EDGES) ? ei[E_EDGES + e] : (e - E_EDGES);
  atomicAdd(&cnt[dst], 1);
}

#define SCAN_BLOCKS ((N_NODES + 255) / 256)

__global__ __launch_bounds__(256) void scan1_kernel(const int* __restrict__ cnt,
                                                    int* __restrict__ incl_buf,
                                                    int* __restrict__ partial) {
  __shared__ int ws[4];
  int tid = threadIdx.x, b = blockIdx.x;
  int wave = tid >> 6, lane = tid & 63;
  int i = b * 256 + tid;
  int v = (i < N_NODES) ? cnt[i] : 0;
  int x = v;
#pragma unroll
  for (int off = 1; off < 64; off <<= 1) {
    int t = __shfl_up(x, off, 64);
    if (lane >= off) x += t;
  }
  if (lane == 63) ws[wave] = x;
  __syncthreads();
  if (tid == 0) {
    int s = 0;
#pragma unroll
    for (int w = 0; w < 4; w++) { int t = ws[w]; ws[w] = s; s += t; }
    partial[b] = s;
  }
  __syncthreads();
  if (i < N_NODES) incl_buf[i] = x + ws[wave];
}

__global__ __launch_bounds__(256) void scan2_kernel(int* __restrict__ partial) {
  __shared__ int ws[4];
  int tid = threadIdx.x;
  int wave = tid >> 6, lane = tid & 63;
  int v = (tid < SCAN_BLOCKS) ? partial[tid] : 0;
  int x = v;
#pragma unroll
  for (int off = 1; off < 64; off <<= 1) {
    int t = __shfl_up(x, off, 64);
    if (lane >= off) x += t;
  }
  if (lane == 63) ws[wave] = x;
  __syncthreads();
  if (tid == 0) {
    int s = 0;
#pragma unroll
    for (int w = 0; w < 4; w++) { int t = ws[w]; ws[w] = s; s += t; }
  }
  __syncthreads();
  partial[tid] = x + ws[wave] - v;
}

__global__ __launch_bounds__(256) void scan3_kernel(const int* __restrict__ cnt,
                                                    int* __restrict__ incl_buf,
                                                    const int* __restrict__ partial,
                                                    int* __restrict__ rowptr,
                                                    int* __restrict__ cursor) {
  int tid = threadIdx.x, b = blockIdx.x;
  int i = b * 256 + tid;
  if (i >= N_NODES) return;
  int incl = incl_buf[i] + partial[b];
  rowptr[i + 1] = incl;
  cursor[i] = incl - cnt[i];
  if (i == 0) rowptr[0] = 0;
}

__global__ void scatter_kernel(const int* __restrict__ ei, int* __restrict__ cursor,
                               int* __restrict__ csr_src) {
  int e = blockIdx.x * blockDim.x + threadIdx.x;
  if (e >= ET) return;
  int src, dst;
  if (e < E_EDGES) { src = ei[e]; dst = ei[E_EDGES + e]; }
  else { src = e - E_EDGES; dst = src; }
  int pos = atomicAdd(&cursor[dst], 1);
  csr_src[pos] = src;
}

// ---------------- 2-term split-bf16 MFMA GEMM (R12 loop + wals-MFMA epilogue) ----------------
// BM=64 (782 blocks), BN=256, BK=32. 4 waves; wave w = head w, 64x64 sub-tile.
// Register double-buffer across K-iters (R12). als/ald computed as an extra
// 16x16 MFMA tile (B = wals vectors, cols 0..7) -- replaces the 256-shuffle
// epilogue with 2 extra MFMA per K-iter. All node buffers padded by 64 rows:
// no bounds checks anywhere (pad rows hold deterministic garbage, never read).

template <int K>
__global__ __launch_bounds__(256) void mfma_gemm_kernel(
    const unsigned short* __restrict__ A,
    const unsigned short* __restrict__ Whi, const unsigned short* __restrict__ Wlo,
    const unsigned short* __restrict__ Walsh, const unsigned short* __restrict__ Walsl,
    _Float16* __restrict__ hbuf16, float* __restrict__ als, float* __restrict__ ald) {
  __shared__ unsigned short As[4 * 64 * 8];       // 4 KB
  __shared__ unsigned short Bs[2][4 * 256 * 8];   // 32 KB

  int t = threadIdx.x;
  int mt = blockIdx.x;
  int w = t >> 6, lane = t & 63, lr = lane & 15, kg = lane >> 4;
  int srow = t >> 2, skg = t & 3;

  f32x4 acc[4][4];
  f32x4 accal[4];
#pragma unroll
  for (int m = 0; m < 4; m++) {
#pragma unroll
    for (int nf = 0; nf < 4; nf++) {
      f32x4 z = {0.f, 0.f, 0.f, 0.f};
      acc[m][nf] = z;
    }
    f32x4 z = {0.f, 0.f, 0.f, 0.f};
    accal[m] = z;
  }

  int agrow = mt * 64 + srow;  // in-bounds: A padded to NPAD rows

  us8 va[2], vb0[2][4], vb1[2][4], wh[2], wl[2];
  // prefetch k-tile 0
  va[0] = *(const us8*)&A[(size_t)agrow * K + skg * 8];
#pragma unroll
  for (int c = 0; c < 4; c++) {
    int n = srow + 64 * c;
    vb0[0][c] = *(const us8*)&Whi[(size_t)n * K + skg * 8];
    vb1[0][c] = *(const us8*)&Wlo[(size_t)n * K + skg * 8];
  }
  wh[0] = *(const us8*)&Walsh[lr * K + kg * 8];
  wl[0] = *(const us8*)&Walsl[lr * K + kg * 8];

#pragma unroll
  for (int k0 = 0; k0 < K; k0 += 32) {
    const int buf = (k0 >> 5) & 1;
    const int nbuf = buf ^ 1;
    __syncthreads();
    *(us8*)&As[(skg * 64 + srow) * 8] = va[buf];
#pragma unroll
    for (int c = 0; c < 4; c++) {
      int n = srow + 64 * c;
      *(us8*)&Bs[0][(skg * 256 + n) * 8] = vb0[buf][c];
      *(us8*)&Bs[1][(skg * 256 + n) * 8] = vb1[buf][c];
    }
    __syncthreads();

    if (k0 + 32 < K) {
      int k1 = k0 + 32;
      va[nbuf] = *(const us8*)&A[(size_t)agrow * K + k1 + skg * 8];
#pragma unroll
      for (int c = 0; c < 4; c++) {
        int n = srow + 64 * c;
        vb0[nbuf][c] = *(const us8*)&Whi[(size_t)n * K + k1 + skg * 8];
        vb1[nbuf][c] = *(const us8*)&Wlo[(size_t)n * K + k1 + skg * 8];
      }
      wh[nbuf] = *(const us8*)&Walsh[lr * K + k1 + kg * 8];
      wl[nbuf] = *(const us8*)&Walsl[lr * K + k1 + kg * 8];
    }

    us8 bh[4], bl[4];
#pragma unroll
    for (int nf = 0; nf < 4; nf++) {
      int n = w * 64 + nf * 16 + lr;
      bh[nf] = *(us8*)&Bs[0][(kg * 256 + n) * 8];
      bl[nf] = *(us8*)&Bs[1][(kg * 256 + n) * 8];
    }
#pragma unroll
    for (int m = 0; m < 4; m++) {
      int row = m * 16 + lr;
      us8 ah = *(us8*)&As[(kg * 64 + row) * 8];
#pragma unroll
      for (int nf = 0; nf < 4; nf++) {
        acc[m][nf] = MFMA16(ah, bh[nf], acc[m][nf]);
        acc[m][nf] = MFMA16(ah, bl[nf], acc[m][nf]);
      }
      accal[m] = MFMA16(ah, wh[buf], accal[m]);
      accal[m] = MFMA16(ah, wl[buf], accal[m]);
    }
  }

  // epilogue: h stores (unconditional, padded) + als/ald from accal (wave 0).
  // C layout: col = nf*16 + lr, row = m*16 + kg*4 + r
  int head = w;
#pragma unroll
  for (int m = 0; m < 4; m++) {
#pragma unroll
    for (int r = 0; r < 4; r++) {
      int grow = mt * 64 + m * 16 + kg * 4 + r;
#pragma unroll
      for (int nf = 0; nf < 4; nf++)
        hbuf16[(size_t)grow * HC + head * 64 + nf * 16 + lr] = (_Float16)acc[m][nf][r];
    }
  }
  if (w == 0) {
    // accal cols: 0..3 = als heads, 4..7 = ald heads (log2e-scaled already)
#pragma unroll
    for (int m = 0; m < 4; m++) {
#pragma unroll
      for (int r = 0; r < 4; r++) {
        int grow = mt * 64 + m * 16 + kg * 4 + r;
        if (lr < 4) als[grow * HEADS + lr] = accal[m][r];
        else if (lr < 8) ald[grow * HEADS + (lr - 4)] = accal[m][r];
      }
    }
  }
}

// ---------------- dual-stream per-destination softmax + aggregate (R7 keeper) ----------------

template <int MODE>
__global__ __launch_bounds__(256) void agg_kernel(
    const _Float16* __restrict__ hbuf16, const float* __restrict__ alsE,
    const float* __restrict__ aldE, const int* __restrict__ rowptr,
    const int* __restrict__ csr_src, const float* __restrict__ bias,
    unsigned short* __restrict__ ohi, float* __restrict__ pooled,
    const int* __restrict__ batch) {
  int wave = threadIdx.x >> 6;
  int lane = threadIdx.x & 63;
  int v0 = blockIdx.x * 8 + wave * 2;
  int v1 = v0 + 1;
  int head = lane >> 4;
  float ald0 = aldE[(unsigned)v0 * HEADS + head];
  float ald1 = aldE[(unsigned)v1 * HEADS + head];
  int beg0 = rowptr[v0], n0 = rowptr[v0 + 1] - beg0;
  int beg1 = rowptr[v1], n1 = rowptr[v1 + 1] - beg1;
  int n = max(n0, n1);

  float den0 = 0.f, den1 = 0.f;
  f32x4 acc0 = {0.f, 0.f, 0.f, 0.f};
  f32x4 acc1 = {0.f, 0.f, 0.f, 0.f};
  const _Float16* hp = hbuf16 + (lane << 2);
#pragma unroll 2
  for (int i = 0; i < n; i++) {
    int s0 = csr_src[beg0 + min(i, n0 - 1)];
    int s1 = csr_src[beg1 + min(i, n1 - 1)];
    float a0 = alsE[(unsigned)s0 * HEADS + head] + ald0;
    float a1 = alsE[(unsigned)s1 * HEADS + head] + ald1;
    a0 = fmaxf(a0, SLOPE * a0);
    a1 = fmaxf(a1, SLOPE * a1);
    float ex0 = (i < n0) ? __builtin_amdgcn_exp2f(a0) : 0.f;
    float ex1 = (i < n1) ? __builtin_amdgcn_exp2f(a1) : 0.f;
    h16x4 h0 = *(const h16x4*)(hp + ((unsigned)s0 << 8));
    h16x4 h1 = *(const h16x4*)(hp + ((unsigned)s1 << 8));
    den0 += ex0; den1 += ex1;
    acc0[0] += (float)h0[0] * ex0; acc0[1] += (float)h0[1] * ex0;
    acc0[2] += (float)h0[2] * ex0; acc0[3] += (float)h0[3] * ex0;
    acc1[0] += (float)h1[0] * ex1; acc1[1] += (float)h1[1] * ex1;
    acc1[2] += (float)h1[2] * ex1; acc1[3] += (float)h1[3] * ex1;
  }
  float inv0 = 1.0f / (den0 + 1e-16f);
  float inv1 = 1.0f / (den1 + 1e-16f);
  float4 bv = *(const float4*)&bias[lane * 4];
  float o0[4], o1[4];
  o0[0] = acc0[0] * inv0 + bv.x; o0[1] = acc0[1] * inv0 + bv.y;
  o0[2] = acc0[2] * inv0 + bv.z; o0[3] = acc0[3] * inv0 + bv.w;
  o1[0] = acc1[0] * inv1 + bv.x; o1[1] = acc1[1] * inv1 + bv.y;
  o1[2] = acc1[2] * inv1 + bv.z; o1[3] = acc1[3] * inv1 + bv.w;

  if (MODE == 0) {
    us4 h0, h1;
#pragma unroll
    for (int j = 0; j < 4; j++) {
      h0[j] = f2bf_rne(fmaxf(o0[j], 0.f));
      h1[j] = f2bf_rne(fmaxf(o1[j], 0.f));
    }
    *(us4*)&ohi[(size_t)v0 * HC + lane * 4] = h0;
    *(us4*)&ohi[(size_t)v1 * HC + lane * 4] = h1;
  } else {
    __shared__ float pacc[8][HC];
    __shared__ int pg[8];
    f32x4 ov0 = {o0[0], o0[1], o0[2], o0[3]};
    f32x4 ov1 = {o1[0], o1[1], o1[2], o1[3]};
    *(f32x4*)&pacc[wave * 2][lane * 4] = ov0;
    *(f32x4*)&pacc[wave * 2 + 1][lane * 4] = ov1;
    if (lane == 0) {
      pg[wave * 2] = batch[v0];
      pg[wave * 2 + 1] = batch[v1];
    }
    __syncthreads();
    int c = threadIdx.x;
    float s = pacc[0][c];
    int gcur = pg[0];
#pragma unroll
    for (int wv = 1; wv < 8; wv++) {
      if (pg[wv] != gcur) {
        atomicAdd(&pooled[gcur * HC + c], s);
        s = 0.f;
        gcur = pg[wv];
      }
      s += pacc[wv][c];
    }
    atomicAdd(&pooled[gcur * HC + c], s);
  }
}

// ---------------- MLP head (fused mean-divide) ----------------

__global__ __launch_bounds__(64) void mlp_kernel(const float* __restrict__ pooled_sum,
                                                 const int* __restrict__ batch,
                                                 const float* __restrict__ w1,
                                                 const float* __restrict__ b1,
                                                 const float* __restrict__ w2,
                                                 const float* __restrict__ b2,
                                                 float* __restrict__ out) {
  int g = blockIdx.x;
  int j = threadIdx.x;
  int lo = 0, hi = N_NODES;
  while (lo < hi) { int mid = (lo + hi) >> 1; if (batch[mid] < g) lo = mid + 1; else hi = mid; }
  int start = lo;
  hi = N_NODES;
  while (lo < hi) { int mid = (lo + hi) >> 1; if (batch[mid] < g + 1) lo = mid + 1; else hi = mid; }
  float invc = 1.0f / fmaxf((float)(lo - start), 1.0f);
  __shared__ float z[HID];
  float acc = 0.f;
  for (int k = 0; k < HC; k++) acc += pooled_sum[g * HC + k] * w1[j * HC + k];
  z[j] = fmaxf(acc * invc + b1[j], 0.f);
  __syncthreads();
  if (j < NC) {
    float o = b2[j];
    for (int k = 0; k < HID; k++) o += z[k] * w2[j * HID + k];
    out[g * NC + j] = o;
  }
}

// ---------------- launch ----------------

extern "C" void kernel_launch(void* const* d_in, const int* in_sizes, int n_in,
                              void* d_out, int out_size, void* d_ws, size_t ws_size,
                              hipStream_t stream) {
  const float* x    = (const float*)d_in[0];
  const int*   ei   = (const int*)d_in[1];
  const int*   batch= (const int*)d_in[2];
  const float* W1   = (const float*)d_in[3];
  const float* as1  = (const float*)d_in[4];
  const float* ad1  = (const float*)d_in[5];
  const float* b1   = (const float*)d_in[6];
  const float* W2   = (const float*)d_in[7];
  const float* as2  = (const float*)d_in[8];
  const float* ad2  = (const float*)d_in[9];
  const float* b2   = (const float*)d_in[10];
  const float* W3   = (const float*)d_in[11];
  const float* as3  = (const float*)d_in[12];
  const float* ad3  = (const float*)d_in[13];
  const float* b3   = (const float*)d_in[14];
  const float* fc1w = (const float*)d_in[15];
  const float* fc1b = (const float*)d_in[16];
  const float* fc2w = (const float*)d_in[17];
  const float* fc2b = (const float*)d_in[18];
  float* out = (float*)d_out;

  char* ws = (char*)d_ws;
  size_t off = 0;
  _Float16* hbuf16 = (_Float16*)(ws + off); off += (size_t)NPAD * HC * 2;
  unsigned short* ahi = (unsigned short*)(ws + off); off += (size_t)NPAD * HC * 2;
  unsigned short* xhi = (unsigned short*)(ws + off); off += (size_t)NPAD * IN_F * 2;
  unsigned short* w1h = (unsigned short*)(ws + off); off += (size_t)HC * IN_F * 2;
  unsigned short* w1l = (unsigned short*)(ws + off); off += (size_t)HC * IN_F * 2;
  unsigned short* w2h = (unsigned short*)(ws + off); off += (size_t)HC * HC * 2;
  unsigned short* w2l = (unsigned short*)(ws + off); off += (size_t)HC * HC * 2;
  unsigned short* w3h = (unsigned short*)(ws + off); off += (size_t)HC * HC * 2;
  unsigned short* w3l = (unsigned short*)(ws + off); off += (size_t)HC * HC * 2;
  unsigned short* wa1h = (unsigned short*)(ws + off); off += (size_t)16 * IN_F * 2;
  unsigned short* wa1l = (unsigned short*)(ws + off); off += (size_t)16 * IN_F * 2;
  unsigned short* wa2h = (unsigned short*)(ws + off); off += (size_t)16 * HC * 2;
  unsigned short* wa2l = (unsigned short*)(ws + off); off += (size_t)16 * HC * 2;
  unsigned short* wa3h = (unsigned short*)(ws + off); off += (size_t)16 * HC * 2;
  unsigned short* wa3l = (unsigned short*)(ws + off); off += (size_t)16 * HC * 2;
  float* als    = (float*)(ws + off); off += (size_t)NPAD * HEADS * 4;
  float* ald    = (float*)(ws + off); off += (size_t)NPAD * HEADS * 4;
  float* pooled = (float*)(ws + off); off += (size_t)G_GRAPHS * HC * 4;
  int*   cnt    = (int*)(ws + off);   off += (size_t)N_NODES * 4;
  int*   cursor = (int*)(ws + off);   off += (size_t)N_NODES * 4;
  int*   csrsrc = (int*)(ws + off);   off += (size_t)ET * 4;
  int*   rowptr = (int*)(ws + off);   off += (size_t)(N_NODES + 1) * 4;
  int*   partial= (int*)(ws + off);   off += 256 * 4;

  // --- fused splits + wals precompute (independent of CSR) ---
  split_all_kernel<<<(QALL + 255) / 256, 256, 0, stream>>>(
      x, W1, W2, W3, as1, ad1, as2, ad2, as3, ad3,
      xhi, w1h, w1l, w2h, w2l, w3h, w3l,
      wa1h, wa1l, wa2h, wa2l, wa3h, wa3l);

  // --- CSR build ---
  hipMemsetAsync(cnt, 0, (size_t)N_NODES * 4, stream);
  hipMemsetAsync(pooled, 0, (size_t)G_GRAPHS * HC * 4, stream);
  count_kernel<<<(ET + 255) / 256, 256, 0, stream>>>(ei, cnt);
  scan1_kernel<<<SCAN_BLOCKS, 256, 0, stream>>>(cnt, cursor, partial);
  scan2_kernel<<<1, 256, 0, stream>>>(partial);
  scan3_kernel<<<SCAN_BLOCKS, 256, 0, stream>>>(cnt, cursor, partial, rowptr, cursor);
  scatter_kernel<<<(ET + 255) / 256, 256, 0, stream>>>(ei, cursor, csrsrc);

  dim3 gemm_grid((N_NODES + 63) / 64);
  int agg_grid = N_NODES / 8;  // exact: 50000 % 8 == 0

  // --- layer 1 ---
  mfma_gemm_kernel<IN_F><<<gemm_grid, 256, 0, stream>>>(xhi, w1h, w1l, wa1h, wa1l, hbuf16, als, ald);
  agg_kernel<0><<<agg_grid, 256, 0, stream>>>(hbuf16, als, ald, rowptr, csrsrc, b1, ahi, nullptr, nullptr);
  // --- layer 2 ---
  mfma_gemm_kernel<HC><<<gemm_grid, 256, 0, stream>>>(ahi, w2h, w2l, wa2h, wa2l, hbuf16, als, ald);
  agg_kernel<0><<<agg_grid, 256, 0, stream>>>(hbuf16, als, ald, rowptr, csrsrc, b2, ahi, nullptr, nullptr);
  // --- layer 3 (fused mean-pool accumulate) ---
  mfma_gemm_kernel<HC><<<gemm_grid, 256, 0, stream>>>(ahi, w3h, w3l, wa3h, wa3l, hbuf16, als, ald);
  agg_kernel<1><<<agg_grid, 256, 0, stream>>>(hbuf16, als, ald, rowptr, csrsrc, b3, nullptr, pooled, batch);

  // --- MLP (with fused mean divide) ---
  mlp_kernel<<<G_GRAPHS, 64, 0, stream>>>(pooled, batch, fc1w, fc1b, fc2w, fc2b, out);
}

// Round 15
// 428.653 us; speedup vs baseline: 1.0942x; 1.0421x over previous
//
#include <hip/hip_runtime.h>
#include <hip/hip_bf16.h>

#define N_NODES 50000
#define E_EDGES 800000
#define ET (E_EDGES + N_NODES)
#define G_GRAPHS 64
#define IN_F 128
#define HID 64
#define HEADS 4
#define HC (HID * HEADS)
#define NC 2
#define SLOPE 0.2f
#define L2E 1.4426950408889634f

typedef float f32x4 __attribute__((ext_vector_type(4)));
typedef __bf16 bf16x8 __attribute__((ext_vector_type(8)));
typedef unsigned short us8 __attribute__((ext_vector_type(8)));
typedef unsigned short us4 __attribute__((ext_vector_type(4)));
typedef _Float16 h16x4 __attribute__((ext_vector_type(4)));

#define MFMA16(a, b, c) \
  __builtin_amdgcn_mfma_f32_16x16x32_bf16(__builtin_bit_cast(bf16x8, (a)), \
                                          __builtin_bit_cast(bf16x8, (b)), (c), 0, 0, 0)

__device__ inline unsigned short f2bf_rne(float f) {
  unsigned u = __builtin_bit_cast(unsigned, f);
  u += 0x7fffu + ((u >> 16) & 1u);
  return (unsigned short)(u >> 16);
}
__device__ inline float bf2f(unsigned short h) {
  unsigned u = ((unsigned)h) << 16;
  return __builtin_bit_cast(float, u);
}

// ---------------- fused split/cast + edge-count kernel ----------------
// Blocks [0, SPLIT_BLOCKS): split x (bf16) and W1..W3 (bf16 hi/lo).
// Blocks [SPLIT_BLOCKS, +CNT_BLOCKS): count edges per destination (cnt zeroed
// by the preceding memsetAsync). Fusing removes a dispatch and overlaps the
// two independent memory-bound workloads.

__device__ inline void split4(const float* __restrict__ in, unsigned short* __restrict__ hi,
                              unsigned short* __restrict__ lo, int i) {
  float4 v = *(const float4*)&in[i];
  float f[4] = {v.x, v.y, v.z, v.w};
  us4 h, l;
#pragma unroll
  for (int j = 0; j < 4; j++) {
    unsigned short hb = f2bf_rne(f[j]);
    h[j] = hb;
    l[j] = f2bf_rne(f[j] - bf2f(hb));
  }
  *(us4*)&hi[i] = h;
  *(us4*)&lo[i] = l;
}

#define QX (N_NODES * IN_F / 4)
#define QW1 (HC * IN_F / 4)
#define QW2 (HC * HC / 4)
#define QTOT (QX + QW1 + 2 * QW2)
#define SPLIT_BLOCKS ((QTOT + 255) / 256)
#define CNT_BLOCKS ((ET + 255) / 256)

__global__ __launch_bounds__(256) void split_count_kernel(
    const float* __restrict__ x, const float* __restrict__ W1,
    const float* __restrict__ W2, const float* __restrict__ W3,
    unsigned short* __restrict__ xhi,
    unsigned short* __restrict__ w1h, unsigned short* __restrict__ w1l,
    unsigned short* __restrict__ w2h, unsigned short* __restrict__ w2l,
    unsigned short* __restrict__ w3h, unsigned short* __restrict__ w3l,
    const int* __restrict__ ei, int* __restrict__ cnt) {
  int b = blockIdx.x;
  if (b >= SPLIT_BLOCKS) {
    int e = (b - SPLIT_BLOCKS) * 256 + threadIdx.x;
    if (e < ET) {
      int dst = (e < E_EDGES) ? ei[E_EDGES + e] : (e - E_EDGES);
      atomicAdd(&cnt[dst], 1);
    }
    return;
  }
  int q = b * 256 + threadIdx.x;
  if (q < QX) {
    int i = q * 4;
    float4 v = *(const float4*)&x[i];
    float f[4] = {v.x, v.y, v.z, v.w};
    us4 h;
#pragma unroll
    for (int j = 0; j < 4; j++) h[j] = f2bf_rne(f[j]);
    *(us4*)&xhi[i] = h;
  } else if (q < QX + QW1) {
    split4(W1, w1h, w1l, (q - QX) * 4);
  } else if (q < QX + QW1 + QW2) {
    split4(W2, w2h, w2l, (q - QX - QW1) * 4);
  } else if (q < QTOT) {
    split4(W3, w3h, w3l, (q - QX - QW1 - QW2) * 4);
  }
}

// ---------------- CSR scan + scatter ----------------

#define SCAN_BLOCKS ((N_NODES + 255) / 256)

__global__ __launch_bounds__(256) void scan1_kernel(const int* __restrict__ cnt,
                                                    int* __restrict__ incl_buf,
                                                    int* __restrict__ partial) {
  __shared__ int ws[4];
  int tid = threadIdx.x, b = blockIdx.x;
  int wave = tid >> 6, lane = tid & 63;
  int i = b * 256 + tid;
  int v = (i < N_NODES) ? cnt[i] : 0;
  int x = v;
#pragma unroll
  for (int off = 1; off < 64; off <<= 1) {
    int t = __shfl_up(x, off, 64);
    if (lane >= off) x += t;
  }
  if (lane == 63) ws[wave] = x;
  __syncthreads();
  if (tid == 0) {
    int s = 0;
#pragma unroll
    for (int w = 0; w < 4; w++) { int t = ws[w]; ws[w] = s; s += t; }
    partial[b] = s;
  }
  __syncthreads();
  if (i < N_NODES) incl_buf[i] = x + ws[wave];
}

__global__ __launch_bounds__(256) void scan2_kernel(int* __restrict__ partial) {
  __shared__ int ws[4];
  int tid = threadIdx.x;
  int wave = tid >> 6, lane = tid & 63;
  int v = (tid < SCAN_BLOCKS) ? partial[tid] : 0;
  int x = v;
#pragma unroll
  for (int off = 1; off < 64; off <<= 1) {
    int t = __shfl_up(x, off, 64);
    if (lane >= off) x += t;
  }
  if (lane == 63) ws[wave] = x;
  __syncthreads();
  if (tid == 0) {
    int s = 0;
#pragma unroll
    for (int w = 0; w < 4; w++) { int t = ws[w]; ws[w] = s; s += t; }
  }
  __syncthreads();
  partial[tid] = x + ws[wave] - v;
}

__global__ __launch_bounds__(256) void scan3_kernel(const int* __restrict__ cnt,
                                                    int* __restrict__ incl_buf,
                                                    const int* __restrict__ partial,
                                                    int* __restrict__ rowptr,
                                                    int* __restrict__ cursor) {
  int tid = threadIdx.x, b = blockIdx.x;
  int i = b * 256 + tid;
  if (i >= N_NODES) return;
  int incl = incl_buf[i] + partial[b];
  rowptr[i + 1] = incl;
  cursor[i] = incl - cnt[i];
  if (i == 0) rowptr[0] = 0;
}

__global__ void scatter_kernel(const int* __restrict__ ei, int* __restrict__ cursor,
                               int* __restrict__ csr_src) {
  int e = blockIdx.x * blockDim.x + threadIdx.x;
  if (e >= ET) return;
  int src, dst;
  if (e < E_EDGES) { src = ei[e]; dst = ei[E_EDGES + e]; }
  else { src = e - E_EDGES; dst = src; }
  int pos = atomicAdd(&cursor[dst], 1);
  csr_src[pos] = src;
}

// ---------------- 2-term split-bf16 MFMA GEMM, register-double-buffered (R12 best) ----------------
// BM=64 (782 blocks), BN=256, BK=32. 4 waves; wave w = head w, 64x64 sub-tile.
// Prefetch tile k+1 into VGPRs during compute of tile k; LDS staging for
// coalesced MFMA fragment reads; shuffle epilogue for als/ald.

template <int K>
__global__ __launch_bounds__(256) void mfma_gemm_kernel(
    const unsigned short* __restrict__ A,
    const unsigned short* __restrict__ Whi, const unsigned short* __restrict__ Wlo,
    const float* __restrict__ a_s, const float* __restrict__ a_d,
    _Float16* __restrict__ hbuf16, float* __restrict__ als, float* __restrict__ ald) {
  __shared__ unsigned short As[4 * 64 * 8];       // 4 KB
  __shared__ unsigned short Bs[2][4 * 256 * 8];   // 32 KB

  int t = threadIdx.x;
  int mt = blockIdx.x;
  int w = t >> 6, lane = t & 63, lr = lane & 15, kg = lane >> 4;
  int srow = t >> 2, skg = t & 3;

  f32x4 acc[4][4];
#pragma unroll
  for (int m = 0; m < 4; m++)
#pragma unroll
    for (int nf = 0; nf < 4; nf++) {
      f32x4 z = {0.f, 0.f, 0.f, 0.f};
      acc[m][nf] = z;
    }

  int agrow = mt * 64 + srow;
  bool avalid = agrow < N_NODES;

  us8 va[2], vb0[2][4], vb1[2][4];
  // prefetch tile 0 into buffer 0
  {
    if (avalid) {
      va[0] = *(const us8*)&A[(size_t)agrow * K + skg * 8];
    } else {
      us8 z = {0, 0, 0, 0, 0, 0, 0, 0};
      va[0] = z;
    }
#pragma unroll
    for (int c = 0; c < 4; c++) {
      int n = srow + 64 * c;
      vb0[0][c] = *(const us8*)&Whi[(size_t)n * K + skg * 8];
      vb1[0][c] = *(const us8*)&Wlo[(size_t)n * K + skg * 8];
    }
  }

#pragma unroll
  for (int k0 = 0; k0 < K; k0 += 32) {
    const int buf = (k0 >> 5) & 1;
    const int nbuf = buf ^ 1;
    __syncthreads();  // all waves done reading LDS from previous tile
    *(us8*)&As[(skg * 64 + srow) * 8] = va[buf];
#pragma unroll
    for (int c = 0; c < 4; c++) {
      int n = srow + 64 * c;
      *(us8*)&Bs[0][(skg * 256 + n) * 8] = vb0[buf][c];
      *(us8*)&Bs[1][(skg * 256 + n) * 8] = vb1[buf][c];
    }
    __syncthreads();  // tile visible

    // issue NEXT tile's loads -- they retire during the MFMA work below
    if (k0 + 32 < K) {
      int k1 = k0 + 32;
      if (avalid) {
        va[nbuf] = *(const us8*)&A[(size_t)agrow * K + k1 + skg * 8];
      } else {
        us8 z = {0, 0, 0, 0, 0, 0, 0, 0};
        va[nbuf] = z;
      }
#pragma unroll
      for (int c = 0; c < 4; c++) {
        int n = srow + 64 * c;
        vb0[nbuf][c] = *(const us8*)&Whi[(size_t)n * K + k1 + skg * 8];
        vb1[nbuf][c] = *(const us8*)&Wlo[(size_t)n * K + k1 + skg * 8];
      }
    }

    us8 bh[4], bl[4];
#pragma unroll
    for (int nf = 0; nf < 4; nf++) {
      int n = w * 64 + nf * 16 + lr;
      bh[nf] = *(us8*)&Bs[0][(kg * 256 + n) * 8];
      bl[nf] = *(us8*)&Bs[1][(kg * 256 + n) * 8];
    }
#pragma unroll
    for (int m = 0; m < 4; m++) {
      int row = m * 16 + lr;
      us8 ah = *(us8*)&As[(kg * 64 + row) * 8];
#pragma unroll
      for (int nf = 0; nf < 4; nf++) {
        acc[m][nf] = MFMA16(ah, bh[nf], acc[m][nf]);
        acc[m][nf] = MFMA16(ah, bl[nf], acc[m][nf]);
      }
    }
  }

  // epilogue: store h (fp16) + reduce als/ald (scaled by log2e) for head w.
  // C layout: col = nf*16 + lr, row = m*16 + kg*4 + r
  int head = w;
  float asv[4], adv[4];
#pragma unroll
  for (int nf = 0; nf < 4; nf++) {
    asv[nf] = a_s[head * HID + nf * 16 + lr];
    adv[nf] = a_d[head * HID + nf * 16 + lr];
  }
#pragma unroll
  for (int m = 0; m < 4; m++) {
#pragma unroll
    for (int r = 0; r < 4; r++) {
      int grow = mt * 64 + m * 16 + kg * 4 + r;
      float ps = 0.f, pd = 0.f;
#pragma unroll
      for (int nf = 0; nf < 4; nf++) {
        float v = acc[m][nf][r];
        ps += v * asv[nf];
        pd += v * adv[nf];
        if (grow < N_NODES)
          hbuf16[(size_t)grow * HC + head * 64 + nf * 16 + lr] = (_Float16)v;
      }
#pragma unroll
      for (int msk = 1; msk < 16; msk <<= 1) {
        ps += __shfl_xor(ps, msk, 64);
        pd += __shfl_xor(pd, msk, 64);
      }
      if (lr == 0 && grow < N_NODES) {
        als[grow * HEADS + head] = ps * L2E;
        ald[grow * HEADS + head] = pd * L2E;
      }
    }
  }
}

// ---------------- dual-stream per-destination softmax + aggregate (R7 keeper) ----------------

template <int MODE>
__global__ __launch_bounds__(256) void agg_kernel(
    const _Float16* __restrict__ hbuf16, const float* __restrict__ alsE,
    const float* __restrict__ aldE, const int* __restrict__ rowptr,
    const int* __restrict__ csr_src, const float* __restrict__ bias,
    unsigned short* __restrict__ ohi, float* __restrict__ pooled,
    const int* __restrict__ batch) {
  int wave = threadIdx.x >> 6;
  int lane = threadIdx.x & 63;
  int v0 = blockIdx.x * 8 + wave * 2;
  int v1 = v0 + 1;
  int head = lane >> 4;
  float ald0 = aldE[(unsigned)v0 * HEADS + head];
  float ald1 = aldE[(unsigned)v1 * HEADS + head];
  int beg0 = rowptr[v0], n0 = rowptr[v0 + 1] - beg0;
  int beg1 = rowptr[v1], n1 = rowptr[v1 + 1] - beg1;
  int n = max(n0, n1);

  float den0 = 0.f, den1 = 0.f;
  f32x4 acc0 = {0.f, 0.f, 0.f, 0.f};
  f32x4 acc1 = {0.f, 0.f, 0.f, 0.f};
  const _Float16* hp = hbuf16 + (lane << 2);
#pragma unroll 2
  for (int i = 0; i < n; i++) {
    int s0 = csr_src[beg0 + min(i, n0 - 1)];
    int s1 = csr_src[beg1 + min(i, n1 - 1)];
    float a0 = alsE[(unsigned)s0 * HEADS + head] + ald0;
    float a1 = alsE[(unsigned)s1 * HEADS + head] + ald1;
    a0 = fmaxf(a0, SLOPE * a0);
    a1 = fmaxf(a1, SLOPE * a1);
    float ex0 = (i < n0) ? __builtin_amdgcn_exp2f(a0) : 0.f;
    float ex1 = (i < n1) ? __builtin_amdgcn_exp2f(a1) : 0.f;
    h16x4 h0 = *(const h16x4*)(hp + ((unsigned)s0 << 8));
    h16x4 h1 = *(const h16x4*)(hp + ((unsigned)s1 << 8));
    den0 += ex0; den1 += ex1;
    acc0[0] += (float)h0[0] * ex0; acc0[1] += (float)h0[1] * ex0;
    acc0[2] += (float)h0[2] * ex0; acc0[3] += (float)h0[3] * ex0;
    acc1[0] += (float)h1[0] * ex1; acc1[1] += (float)h1[1] * ex1;
    acc1[2] += (float)h1[2] * ex1; acc1[3] += (float)h1[3] * ex1;
  }
  float inv0 = 1.0f / (den0 + 1e-16f);
  float inv1 = 1.0f / (den1 + 1e-16f);
  float4 bv = *(const float4*)&bias[lane * 4];
  float o0[4], o1[4];
  o0[0] = acc0[0] * inv0 + bv.x; o0[1] = acc0[1] * inv0 + bv.y;
  o0[2] = acc0[2] * inv0 + bv.z; o0[3] = acc0[3] * inv0 + bv.w;
  o1[0] = acc1[0] * inv1 + bv.x; o1[1] = acc1[1] * inv1 + bv.y;
  o1[2] = acc1[2] * inv1 + bv.z; o1[3] = acc1[3] * inv1 + bv.w;

  if (MODE == 0) {
    us4 h0, h1;
#pragma unroll
    for (int j = 0; j < 4; j++) {
      h0[j] = f2bf_rne(fmaxf(o0[j], 0.f));
      h1[j] = f2bf_rne(fmaxf(o1[j], 0.f));
    }
    *(us4*)&ohi[(size_t)v0 * HC + lane * 4] = h0;
    *(us4*)&ohi[(size_t)v1 * HC + lane * 4] = h1;
  } else {
    __shared__ float pacc[8][HC];
    __shared__ int pg[8];
    f32x4 ov0 = {o0[0], o0[1], o0[2], o0[3]};
    f32x4 ov1 = {o1[0], o1[1], o1[2], o1[3]};
    *(f32x4*)&pacc[wave * 2][lane * 4] = ov0;
    *(f32x4*)&pacc[wave * 2 + 1][lane * 4] = ov1;
    if (lane == 0) {
      pg[wave * 2] = batch[v0];
      pg[wave * 2 + 1] = batch[v1];
    }
    __syncthreads();
    int c = threadIdx.x;
    float s = pacc[0][c];
    int gcur = pg[0];
#pragma unroll
    for (int wv = 1; wv < 8; wv++) {
      if (pg[wv] != gcur) {
        atomicAdd(&pooled[gcur * HC + c], s);
        s = 0.f;
        gcur = pg[wv];
      }
      s += pacc[wv][c];
    }
    atomicAdd(&pooled[gcur * HC + c], s);
  }
}

// ---------------- MLP head (fused mean-divide) ----------------

__global__ __launch_bounds__(64) void mlp_kernel(const float* __restrict__ pooled_sum,
                                                 const int* __restrict__ batch,
                                                 const float* __restrict__ w1,
                                                 const float* __restrict__ b1,
                                                 const float* __restrict__ w2,
                                                 const float* __restrict__ b2,
                                                 float* __restrict__ out) {
  int g = blockIdx.x;
  int j = threadIdx.x;
  int lo = 0, hi = N_NODES;
  while (lo < hi) { int mid = (lo + hi) >> 1; if (batch[mid] < g) lo = mid + 1; else hi = mid; }
  int start = lo;
  hi = N_NODES;
  while (lo < hi) { int mid = (lo + hi) >> 1; if (batch[mid] < g + 1) lo = mid + 1; else hi = mid; }
  float invc = 1.0f / fmaxf((float)(lo - start), 1.0f);
  __shared__ float z[HID];
  float acc = 0.f;
  for (int k = 0; k < HC; k++) acc += pooled_sum[g * HC + k] * w1[j * HC + k];
  z[j] = fmaxf(acc * invc + b1[j], 0.f);
  __syncthreads();
  if (j < NC) {
    float o = b2[j];
    for (int k = 0; k < HID; k++) o += z[k] * w2[j * HID + k];
    out[g * NC + j] = o;
  }
}

// ---------------- launch ----------------

extern "C" void kernel_launch(void* const* d_in, const int* in_sizes, int n_in,
                              void* d_out, int out_size, void* d_ws, size_t ws_size,
                              hipStream_t stream) {
  const float* x    = (const float*)d_in[0];
  const int*   ei   = (const int*)d_in[1];
  const int*   batch= (const int*)d_in[2];
  const float* W1   = (const float*)d_in[3];
  const float* as1  = (const float*)d_in[4];
  const float* ad1  = (const float*)d_in[5];
  const float* b1   = (const float*)d_in[6];
  const float* W2   = (const float*)d_in[7];
  const float* as2  = (const float*)d_in[8];
  const float* ad2  = (const float*)d_in[9];
  const float* b2   = (const float*)d_in[10];
  const float* W3   = (const float*)d_in[11];
  const float* as3  = (const float*)d_in[12];
  const float* ad3  = (const float*)d_in[13];
  const float* b3   = (const float*)d_in[14];
  const float* fc1w = (const float*)d_in[15];
  const float* fc1b = (const float*)d_in[16];
  const float* fc2w = (const float*)d_in[17];
  const float* fc2b = (const float*)d_in[18];
  float* out = (float*)d_out;

  char* ws = (char*)d_ws;
  size_t off = 0;
  _Float16* hbuf16 = (_Float16*)(ws + off); off += (size_t)N_NODES * HC * 2;
  unsigned short* ahi = (unsigned short*)(ws + off); off += (size_t)N_NODES * HC * 2;
  unsigned short* xhi = (unsigned short*)(ws + off); off += (size_t)N_NODES * IN_F * 2;
  unsigned short* w1h = (unsigned short*)(ws + off); off += (size_t)HC * IN_F * 2;
  unsigned short* w1l = (unsigned short*)(ws + off); off += (size_t)HC * IN_F * 2;
  unsigned short* w2h = (unsigned short*)(ws + off); off += (size_t)HC * HC * 2;
  unsigned short* w2l = (unsigned short*)(ws + off); off += (size_t)HC * HC * 2;
  unsigned short* w3h = (unsigned short*)(ws + off); off += (size_t)HC * HC * 2;
  unsigned short* w3l = (unsigned short*)(ws + off); off += (size_t)HC * HC * 2;
  float* als    = (float*)(ws + off); off += (size_t)N_NODES * HEADS * 4;
  float* ald    = (float*)(ws + off); off += (size_t)N_NODES * HEADS * 4;
  float* pooled = (float*)(ws + off); off += (size_t)G_GRAPHS * HC * 4;
  int*   cnt    = (int*)(ws + off);   off += (size_t)N_NODES * 4;
  int*   cursor = (int*)(ws + off);   off += (size_t)N_NODES * 4;
  int*   csrsrc = (int*)(ws + off);   off += (size_t)ET * 4;
  int*   rowptr = (int*)(ws + off);   off += (size_t)(N_NODES + 1) * 4;
  int*   partial= (int*)(ws + off);   off += 256 * 4;

  // --- memsets first (cnt must be zero before fused count blocks run) ---
  hipMemsetAsync(cnt, 0, (size_t)N_NODES * 4, stream);
  hipMemsetAsync(pooled, 0, (size_t)G_GRAPHS * HC * 4, stream);

  // --- fused splits + edge count (one dispatch) ---
  split_count_kernel<<<SPLIT_BLOCKS + CNT_BLOCKS, 256, 0, stream>>>(
      x, W1, W2, W3, xhi, w1h, w1l, w2h, w2l, w3h, w3l, ei, cnt);

  // --- CSR scan + scatter ---
  scan1_kernel<<<SCAN_BLOCKS, 256, 0, stream>>>(cnt, cursor, partial);
  scan2_kernel<<<1, 256, 0, stream>>>(partial);
  scan3_kernel<<<SCAN_BLOCKS, 256, 0, stream>>>(cnt, cursor, partial, rowptr, cursor);
  scatter_kernel<<<(ET + 255) / 256, 256, 0, stream>>>(ei, cursor, csrsrc);

  dim3 gemm_grid((N_NODES + 63) / 64);
  int agg_grid = N_NODES / 8;  // exact: 50000 % 8 == 0

  // --- layer 1 ---
  mfma_gemm_kernel<IN_F><<<gemm_grid, 256, 0, stream>>>(xhi, w1h, w1l, as1, ad1, hbuf16, als, ald);
  agg_kernel<0><<<agg_grid, 256, 0, stream>>>(hbuf16, als, ald, rowptr, csrsrc, b1, ahi, nullptr, nullptr);
  // --- layer 2 ---
  mfma_gemm_kernel<HC><<<gemm_grid, 256, 0, stream>>>(ahi, w2h, w2l, as2, ad2, hbuf16, als, ald);
  agg_kernel<0><<<agg_grid, 256, 0, stream>>>(hbuf16, als, ald, rowptr, csrsrc, b2, ahi, nullptr, nullptr);
  // --- layer 3 (fused mean-pool accumulate) ---
  mfma_gemm_kernel<HC><<<gemm_grid, 256, 0, stream>>>(ahi, w3h, w3l, as3, ad3, hbuf16, als, ald);
  agg_kernel<1><<<agg_grid, 256, 0, stream>>>(hbuf16, als, ald, rowptr, csrsrc, b3, nullptr, pooled, batch);

  // --- MLP (with fused mean divide) ---
  mlp_kernel<<<G_GRAPHS, 64, 0, stream>>>(pooled, batch, fc1w, fc1b, fc2w, fc2b, out);
}